// Round 3
// baseline (654.296 us; speedup 1.0000x reference)
//
#include <hip/hip_runtime.h>
#include <stdint.h>

typedef unsigned short u16;
typedef unsigned int u32;
using short8 = __attribute__((ext_vector_type(8))) short;   // 8 bf16
using f32x4  = __attribute__((ext_vector_type(4))) float;

#define BDIM 16
#define CDIM 512
#define KLAT 64
#define NTOK 4096

__device__ __forceinline__ u16 f2bf(float x) {
  union { float f; u32 u; } a; a.f = x;
  u32 r = a.u + 0x7FFFu + ((a.u >> 16) & 1u);   // RNE
  return (u16)(r >> 16);
}
__device__ __forceinline__ u32 pack2(float a, float b) {
  return (u32)f2bf(a) | ((u32)f2bf(b) << 16);
}

// ---------------------------------------------------------------------------
// Setup: W0T[c][k] = sum_o lin0[k][o]*conv1[o][c];  b0[k] = lin0[k]·conv1_b;
//        lin1T[k][c] = lin1[c][k];  cw_bf = bf16(conv2_w)
// ---------------------------------------------------------------------------
__global__ __launch_bounds__(256) void k_setup(
    const float* __restrict__ conv1_w, const float* __restrict__ conv1_b,
    const float* __restrict__ lin0_w,  const float* __restrict__ lin1_w,
    const float* __restrict__ conv2_w,
    float* __restrict__ w0t, float* __restrict__ b0,
    float* __restrict__ lin1t, u16* __restrict__ cwbf)
{
  const int bid = blockIdx.x;
  const int t = threadIdx.x;
  if (bid < 128) {
    // 16 k-blocks(4) x 8 c-blocks(64); lane=c (coalesced conv1 col), k wave-uniform
    const int kb = bid & 15, cb = bid >> 4;
    const int lane = t & 63;
    int k = kb * 4 + (t >> 6);
    k = __builtin_amdgcn_readfirstlane(k);
    const int c = cb * 64 + lane;
    float acc = 0.f;
    const float* l0 = lin0_w + (size_t)k * CDIM;   // scalar loads
    const float* cw = conv1_w + c;
#pragma unroll 4
    for (int o = 0; o < CDIM; ++o)
      acc = fmaf(l0[o], cw[(size_t)o * CDIM], acc);
    w0t[c * KLAT + k] = acc;
  } else if (bid == 128) {
    if (t < KLAT) {
      float acc = 0.f;
      for (int c = 0; c < CDIM; ++c) acc = fmaf(lin0_w[t * CDIM + c], conv1_b[c], acc);
      b0[t] = acc;
    }
  } else if (bid < 193) {
    // conv2_w -> bf16, 65536 float4 over 64 blocks
    const int b2 = bid - 129;
    const float4* src = (const float4*)conv2_w;
#pragma unroll
    for (int i = 0; i < 4; ++i) {
      int idx = (b2 * 256 + t) + i * 16384;
      float4 v = src[idx];
      uint2 o;
      o.x = pack2(v.x, v.y);
      o.y = pack2(v.z, v.w);
      *(uint2*)(cwbf + (size_t)idx * 4) = o;
    }
  } else {
    // lin1T[k*512+c] = lin1_w[c*64+k]; coalesced writes
    const int b2 = bid - 193;
#pragma unroll
    for (int i = 0; i < 4; ++i) {
      int flat = b2 * 1024 + i * 256 + t;          // flat = k*512 + c
      int k = flat >> 9, c = flat & 511;
      lin1t[flat] = lin1_w[c * KLAT + k];
    }
  }
}

// ---------------------------------------------------------------------------
// K1: partial logits.  part[b][k][n] = sum_{c in half} W0T[c][k]*x[b][c][n]
// block 256 = 64 lanes (4 n each, float4) x 4 waves (16 k each).
// grid (16 n-tiles, 16 b, 2 c-halves).  Depth-2 prefetch of 4 float4 rows.
// acc[16] float4 = 64 VGPR; 16 uniform w-loads per c-step (low SGPR pressure).
// ---------------------------------------------------------------------------
__global__ __launch_bounds__(256) void k_logits(
    const float* __restrict__ x, const float* __restrict__ w0t,
    float* __restrict__ part0, float* __restrict__ part1)
{
  const int t = threadIdx.x;
  const int nf4 = t & 63;
  const int k0 = __builtin_amdgcn_readfirstlane((t >> 6) * 16);
  const int nb = blockIdx.x, b = blockIdx.y, ch = blockIdx.z;

  const float* xp = x + (size_t)b * CDIM * NTOK + (size_t)ch * 256 * NTOK
                      + nb * 256 + nf4 * 4;
  const float* wbase = w0t + (ch * 256) * KLAT + k0;

  float4 acc[16];
#pragma unroll
  for (int j = 0; j < 16; ++j) acc[j] = (float4){0.f, 0.f, 0.f, 0.f};

  float4 xv[4];
#pragma unroll
  for (int u = 0; u < 4; ++u) xv[u] = *(const float4*)(xp + (size_t)u * NTOK);

  for (int cc = 0; cc < 256; cc += 4) {
    float4 nx[4];
    const int cn = (cc + 4) & 255;        // wraps to 0 on last iter (in-bounds)
#pragma unroll
    for (int u = 0; u < 4; ++u) nx[u] = *(const float4*)(xp + (size_t)(cn + u) * NTOK);
#pragma unroll
    for (int u = 0; u < 4; ++u) {
      const float* wp = wbase + (cc + u) * KLAT;   // uniform -> s_load
#pragma unroll
      for (int j = 0; j < 16; ++j) {
        const float wj = wp[j];
        acc[j].x = fmaf(wj, xv[u].x, acc[j].x);
        acc[j].y = fmaf(wj, xv[u].y, acc[j].y);
        acc[j].z = fmaf(wj, xv[u].z, acc[j].z);
        acc[j].w = fmaf(wj, xv[u].w, acc[j].w);
      }
    }
#pragma unroll
    for (int u = 0; u < 4; ++u) xv[u] = nx[u];
  }

  float* op = (ch ? part1 : part0)
            + ((size_t)(b * KLAT + k0)) * NTOK + nb * 256 + nf4 * 4;
#pragma unroll
  for (int j = 0; j < 16; ++j) *(float4*)(op + (size_t)j * NTOK) = acc[j];
}

// ---------------------------------------------------------------------------
// K2: attn = softmax over n of (part0 + part1 + b0[k]); in-place into part0.
// 1024 blocks = (b,k) rows.
// ---------------------------------------------------------------------------
__global__ __launch_bounds__(256) void k_softmax(
    float* __restrict__ p0, const float* __restrict__ p1,
    const float* __restrict__ b0)
{
  __shared__ float red[4], red2[4];
  const int t = threadIdx.x;
  const int row = blockIdx.x;
  const float bias = b0[row & 63];
  float* pr = p0 + (size_t)row * NTOK;
  const float* qr = p1 + (size_t)row * NTOK;
  float4 v[4];
#pragma unroll
  for (int i = 0; i < 4; ++i) {
    float4 a = ((const float4*)pr)[t + i * 256];
    float4 c = ((const float4*)qr)[t + i * 256];
    v[i].x = a.x + c.x + bias; v[i].y = a.y + c.y + bias;
    v[i].z = a.z + c.z + bias; v[i].w = a.w + c.w + bias;
  }
  float m = v[0].x;
#pragma unroll
  for (int i = 0; i < 4; ++i)
    m = fmaxf(m, fmaxf(fmaxf(v[i].x, v[i].y), fmaxf(v[i].z, v[i].w)));
#pragma unroll
  for (int o = 1; o < 64; o <<= 1) m = fmaxf(m, __shfl_xor(m, o));
  const int wv = t >> 6, lane = t & 63;
  if (lane == 0) red[wv] = m;
  __syncthreads();
  m = fmaxf(fmaxf(red[0], red[1]), fmaxf(red[2], red[3]));
  float s = 0.f;
#pragma unroll
  for (int i = 0; i < 4; ++i) {
    v[i].x = __expf(v[i].x - m); s += v[i].x;
    v[i].y = __expf(v[i].y - m); s += v[i].y;
    v[i].z = __expf(v[i].z - m); s += v[i].z;
    v[i].w = __expf(v[i].w - m); s += v[i].w;
  }
#pragma unroll
  for (int o = 1; o < 64; o <<= 1) s += __shfl_xor(s, o);
  if (lane == 0) red2[wv] = s;
  __syncthreads();
  s = red2[0] + red2[1] + red2[2] + red2[3];
  const float inv = 1.f / s;
#pragma unroll
  for (int i = 0; i < 4; ++i) {
    v[i].x *= inv; v[i].y *= inv; v[i].z *= inv; v[i].w *= inv;
    ((float4*)pr)[t + i * 256] = v[i];
  }
}

// ---------------------------------------------------------------------------
// K3: y2[b][c][n] = (sum_k lin1T[k][c]*attn[k][n]) / (1e-9 + sum_k attn[k][n])
// tile: 64k x 256n attn in LDS (64KB); block handles 128 c. y2 := d_out scratch.
// ---------------------------------------------------------------------------
__global__ __launch_bounds__(256) void k_lin1(
    const float* __restrict__ attn, const float* __restrict__ lin1t,
    float* __restrict__ y2)
{
  __shared__ float as_[KLAT][256];
  const int n0 = blockIdx.x * 256, c0 = blockIdx.y * 128, b = blockIdx.z;
  const int t = threadIdx.x;
#pragma unroll
  for (int i = 0; i < 16; ++i) {
    int f4 = t + i * 256;                 // 4096 float4
    int row = f4 >> 6, col = (f4 & 63) * 4;
    float4 v = *(const float4*)(attn + ((size_t)(b * KLAT + row)) * NTOK + n0 + col);
    *(float4*)&as_[row][col] = v;
  }
  __syncthreads();
  {
    float s = 0.f;
#pragma unroll
    for (int k = 0; k < KLAT; ++k) s += as_[k][t];
    float inv = 1.f / (1e-9f + s);
#pragma unroll
    for (int k = 0; k < KLAT; ++k) as_[k][t] *= inv;
  }
  __syncthreads();
  for (int cb = 0; cb < 4; ++cb) {
    const int cbase = c0 + cb * 32;
    float acc[32];
#pragma unroll
    for (int i = 0; i < 32; ++i) acc[i] = 0.f;
    for (int k = 0; k < KLAT; ++k) {
      float av = as_[k][t];
      const float* lp = lin1t + k * CDIM + cbase;  // uniform -> s_load
#pragma unroll
      for (int i = 0; i < 32; ++i) acc[i] = fmaf(lp[i], av, acc[i]);
    }
    float* op = y2 + ((size_t)(b * CDIM + cbase)) * NTOK + n0 + t;
#pragma unroll
    for (int i = 0; i < 32; ++i) op[(size_t)i * NTOK] = acc[i];
  }
}

// ---------------------------------------------------------------------------
// K4: rank + transpose. Each contiguous 512-chunk (fixed b,c; 512 n) gets its
// 256th-largest as threshold; scale 0.75/1.25; write yr^T[b][n][c] bf16.
// Count via __popcll(__ballot(key>=mid)) -- scalar-pipe reduction, no shfl.
// LDS: pitch 512 floats + per-row float4-granule rotation (row + row>>3)
// -> conflict-free b128 search reads AND conflict-free scalar transpose reads.
// ---------------------------------------------------------------------------
__global__ __launch_bounds__(256) void k_rank(
    const float* __restrict__ y2, u16* __restrict__ yrt)
{
  __shared__ float tile[32 * 512];        // exactly 64 KiB
  const int n0 = blockIdx.x * 512, c0 = blockIdx.y * 32, b = blockIdx.z;
  const int t = threadIdx.x;
  // global -> LDS (rotated layout): phys_col4 = (col4 + row + (row>>3)) & 127
#pragma unroll
  for (int i = 0; i < 16; ++i) {
    int f4 = t + i * 256;                 // 4096 float4 = 32 rows x 128 col4
    int row = f4 >> 7, col4 = f4 & 127;
    float4 v = *(const float4*)(y2 + ((size_t)(b * CDIM + c0 + row)) * NTOK + n0 + col4 * 4);
    int phys4 = (col4 + row + (row >> 3)) & 127;
    *(float4*)&tile[row * 512 + phys4 * 4] = v;
  }
  __syncthreads();
  const int wv = t >> 6, lane = t & 63;
  for (int r = 0; r < 8; ++r) {
    const int row = wv * 8 + r;
    const int rot = row + (row >> 3);
    const int c4a = (lane + rot) & 127;          // logical col4 = lane
    const int c4b = (64 + lane + rot) & 127;     // logical col4 = 64 + lane
    float* pa = &tile[row * 512 + c4a * 4];
    float* pb = &tile[row * 512 + c4b * 4];
    float4 va = *(const float4*)pa;
    float4 vb = *(const float4*)pb;
    float v[8] = {va.x, va.y, va.z, va.w, vb.x, vb.y, vb.z, vb.w};
    u32 key[8];
#pragma unroll
    for (int j = 0; j < 8; ++j) {
      u32 u = __float_as_uint(v[j]);
      key[j] = (u & 0x80000000u) ? ~u : (u | 0x80000000u);
    }
    // binary search for threshold key: invariant cnt(>=lo) >= 256 > cnt(>=hi+1)
    u32 lo = 0u, hi = 0xFFFFFFFFu;
    u32 thr;
    for (;;) {
      u32 d = hi - lo;
      u32 mid = lo + (d >> 1) + (d & 1u);
      int cnt = 0;
#pragma unroll
      for (int j = 0; j < 8; ++j)
        cnt += (int)__popcll(__ballot(key[j] >= mid));
      if (cnt == 256) { thr = mid; break; }   // mid in (v257, v256]: exact classes
      if (cnt > 256) lo = mid; else hi = mid - 1u;
      if (lo >= hi) { thr = lo; break; }      // exact v256 (duplicate-safe)
    }
    float4 oa, ob;
    oa.x = (key[0] < thr) ? 0.75f * v[0] : 1.25f * v[0];
    oa.y = (key[1] < thr) ? 0.75f * v[1] : 1.25f * v[1];
    oa.z = (key[2] < thr) ? 0.75f * v[2] : 1.25f * v[2];
    oa.w = (key[3] < thr) ? 0.75f * v[3] : 1.25f * v[3];
    ob.x = (key[4] < thr) ? 0.75f * v[4] : 1.25f * v[4];
    ob.y = (key[5] < thr) ? 0.75f * v[5] : 1.25f * v[5];
    ob.z = (key[6] < thr) ? 0.75f * v[6] : 1.25f * v[6];
    ob.w = (key[7] < thr) ? 0.75f * v[7] : 1.25f * v[7];
    *(float4*)pa = oa;
    *(float4*)pb = ob;
  }
  __syncthreads();
  // transposed bf16 write: yrt[b][n][c]; read rotated layout
#pragma unroll
  for (int i = 0; i < 8; ++i) {
    int nr = (t >> 2) + i * 64;
    int cs = (t & 3) * 8;
    float w[8];
#pragma unroll
    for (int j = 0; j < 8; ++j) {
      int row = cs + j;
      int phys4 = ((nr >> 2) + row + (row >> 3)) & 127;
      w[j] = tile[row * 512 + phys4 * 4 + (nr & 3)];
    }
    uint4 o;
    o.x = pack2(w[0], w[1]); o.y = pack2(w[2], w[3]);
    o.z = pack2(w[4], w[5]); o.w = pack2(w[6], w[7]);
    *(uint4*)(yrt + ((size_t)(b * NTOK + n0 + nr)) * CDIM + c0 + cs) = o;
  }
}

// ---------------------------------------------------------------------------
// K5: out = relu(relu(conv2_w @ yr) + x).  bf16 MFMA 16x16x32, 128x128 tile,
// BK=64, 4 waves each 64x64. A = cw_bf [o][c], B = yr^T [n][c] (both K-contig).
// ---------------------------------------------------------------------------
__global__ __launch_bounds__(256) void k_conv2(
    const u16* __restrict__ cwbf, const u16* __restrict__ yrt,
    const float* __restrict__ x, float* __restrict__ out)
{
  __shared__ u16 As[128 * 72];            // pitch 72 bf16 (pad 8) -> 144B rows
  __shared__ u16 Bs[128 * 72];
  const int nb = blockIdx.x, mb = blockIdx.y, b = blockIdx.z;
  const int t = threadIdx.x;
  const int wv = t >> 6, lane = t & 63;
  const int wm = wv >> 1, wn = wv & 1;
  const int quad = lane >> 4, l15 = lane & 15;
  f32x4 acc[4][4];
#pragma unroll
  for (int mi = 0; mi < 4; ++mi)
#pragma unroll
    for (int ni = 0; ni < 4; ++ni) acc[mi][ni] = (f32x4){0.f, 0.f, 0.f, 0.f};

  for (int kc = 0; kc < 8; ++kc) {
#pragma unroll
    for (int i = 0; i < 4; ++i) {
      int ch = t + i * 256;               // 1024 chunks of 8 bf16
      int row = ch >> 3, col = (ch & 7) * 8;
      uint4 a = *(const uint4*)(cwbf + ((size_t)(mb * 128 + row)) * CDIM + kc * 64 + col);
      *(uint4*)&As[row * 72 + col] = a;
      uint4 bb = *(const uint4*)(yrt + ((size_t)(b * NTOK + nb * 128 + row)) * CDIM + kc * 64 + col);
      *(uint4*)&Bs[row * 72 + col] = bb;
    }
    __syncthreads();
#pragma unroll
    for (int kk = 0; kk < 2; ++kk) {
      short8 af[4], bf_[4];
#pragma unroll
      for (int mi = 0; mi < 4; ++mi)
        af[mi] = *(short8*)&As[(wm * 64 + mi * 16 + l15) * 72 + kk * 32 + quad * 8];
#pragma unroll
      for (int ni = 0; ni < 4; ++ni)
        bf_[ni] = *(short8*)&Bs[(wn * 64 + ni * 16 + l15) * 72 + kk * 32 + quad * 8];
#pragma unroll
      for (int mi = 0; mi < 4; ++mi)
#pragma unroll
        for (int ni = 0; ni < 4; ++ni)
          acc[mi][ni] = __builtin_amdgcn_mfma_f32_16x16x32_bf16(
              af[mi], bf_[ni], acc[mi][ni], 0, 0, 0);
    }
    __syncthreads();
  }
  // epilogue: relu -> +x -> relu   (C/D layout: col=lane&15, row=quad*4+reg)
#pragma unroll
  for (int mi = 0; mi < 4; ++mi) {
#pragma unroll
    for (int ni = 0; ni < 4; ++ni) {
#pragma unroll
      for (int r = 0; r < 4; ++r) {
        int row = mb * 128 + wm * 64 + mi * 16 + quad * 4 + r;
        int col = nb * 128 + wn * 64 + ni * 16 + l15;
        size_t off = ((size_t)(b * CDIM + row)) * NTOK + col;
        float g = fmaxf(acc[mi][ni][r], 0.f) + x[off];
        out[off] = fmaxf(g, 0.f);
      }
    }
  }
}

// ---------------------------------------------------------------------------
extern "C" void kernel_launch(void* const* d_in, const int* in_sizes, int n_in,
                              void* d_out, int out_size, void* d_ws, size_t ws_size,
                              hipStream_t stream)
{
  const float* x       = (const float*)d_in[0];
  const float* conv1_w = (const float*)d_in[1];
  const float* conv1_b = (const float*)d_in[2];
  const float* lin0_w  = (const float*)d_in[3];
  const float* lin1_w  = (const float*)d_in[4];
  const float* conv2_w = (const float*)d_in[5];
  float* out = (float*)d_out;

  char* ws = (char*)d_ws;
  float* attn  = (float*)ws;                               // part0/attn: 16,777,216 B
  u16*   yrt   = (u16*)(ws + 16777216);                    // 67,108,864 B
  char*  wsm   = ws + 16777216 + 67108864;
  float* w0t   = (float*)wsm;                              // 131072 B
  float* b0    = (float*)(wsm + 131072);                   // 256 B
  float* lin1t = (float*)(wsm + 131072 + 256);             // 131072 B
  u16*   cwbf  = (u16*)(wsm + 131072 + 256 + 131072);      // 524288 B
  float* part1 = out;                // d_out reused: consumed by softmax before lin1
  float* y2    = out;                // then d_out reused as y2 scratch

  k_setup  <<<225, 256, 0, stream>>>(conv1_w, conv1_b, lin0_w, lin1_w, conv2_w,
                                     w0t, b0, lin1t, cwbf);
  k_logits <<<dim3(16, 16, 2), 256, 0, stream>>>(x, w0t, attn, part1);
  k_softmax<<<1024, 256, 0, stream>>>(attn, part1, b0);
  k_lin1   <<<dim3(16, 4, 16), 256, 0, stream>>>(attn, lin1t, y2);
  k_rank   <<<dim3(8, 16, 16), 256, 0, stream>>>(y2, yrt);
  k_conv2  <<<dim3(32, 4, 16), 256, 0, stream>>>(cwbf, yrt, x, out);
}

// Round 4
// 604.532 us; speedup vs baseline: 1.0823x; 1.0823x over previous
//
#include <hip/hip_runtime.h>
#include <stdint.h>

typedef unsigned short u16;
typedef unsigned int u32;
using short8 = __attribute__((ext_vector_type(8))) short;   // 8 bf16
using f32x4  = __attribute__((ext_vector_type(4))) float;

#define BDIM 16
#define CDIM 512
#define KLAT 64
#define NTOK 4096

__device__ __forceinline__ u16 f2bf(float x) {
  union { float f; u32 u; } a; a.f = x;
  u32 r = a.u + 0x7FFFu + ((a.u >> 16) & 1u);   // RNE
  return (u16)(r >> 16);
}
__device__ __forceinline__ u32 pack2(float a, float b) {
  return (u32)f2bf(a) | ((u32)f2bf(b) << 16);
}

// ---------------------------------------------------------------------------
// Setup: w0bf[k][c] = bf16(sum_o lin0[k][o]*conv1[o][c]); b0[k] = lin0[k]·conv1_b;
//        lin1T[k][c] = lin1[c][k];  cw_bf = bf16(conv2_w)
// ---------------------------------------------------------------------------
__global__ __launch_bounds__(256) void k_setup(
    const float* __restrict__ conv1_w, const float* __restrict__ conv1_b,
    const float* __restrict__ lin0_w,  const float* __restrict__ lin1_w,
    const float* __restrict__ conv2_w,
    u16* __restrict__ w0bf, float* __restrict__ b0,
    float* __restrict__ lin1t, u16* __restrict__ cwbf)
{
  const int bid = blockIdx.x;
  const int t = threadIdx.x;
  if (bid < 128) {
    // 16 k-blocks(4) x 8 c-blocks(64); lane=c (coalesced conv1 col), k wave-uniform
    const int kb = bid & 15, cb = bid >> 4;
    const int lane = t & 63;
    int k = kb * 4 + (t >> 6);
    k = __builtin_amdgcn_readfirstlane(k);
    const int c = cb * 64 + lane;
    float acc = 0.f;
    const float* l0 = lin0_w + (size_t)k * CDIM;   // scalar loads
    const float* cw = conv1_w + c;
#pragma unroll 4
    for (int o = 0; o < CDIM; ++o)
      acc = fmaf(l0[o], cw[(size_t)o * CDIM], acc);
    w0bf[k * CDIM + c] = f2bf(acc);
  } else if (bid == 128) {
    if (t < KLAT) {
      float acc = 0.f;
      for (int c = 0; c < CDIM; ++c) acc = fmaf(lin0_w[t * CDIM + c], conv1_b[c], acc);
      b0[t] = acc;
    }
  } else if (bid < 193) {
    // conv2_w -> bf16, 65536 float4 over 64 blocks
    const int b2 = bid - 129;
    const float4* src = (const float4*)conv2_w;
#pragma unroll
    for (int i = 0; i < 4; ++i) {
      int idx = (b2 * 256 + t) + i * 16384;
      float4 v = src[idx];
      uint2 o;
      o.x = pack2(v.x, v.y);
      o.y = pack2(v.z, v.w);
      *(uint2*)(cwbf + (size_t)idx * 4) = o;
    }
  } else {
    // lin1T[k*512+c] = lin1_w[c*64+k]; coalesced writes
    const int b2 = bid - 193;
#pragma unroll
    for (int i = 0; i < 4; ++i) {
      int flat = b2 * 1024 + i * 256 + t;          // flat = k*512 + c
      int k = flat >> 9, c = flat & 511;
      lin1t[flat] = lin1_w[c * KLAT + k];
    }
  }
}

// ---------------------------------------------------------------------------
// K0: transpose-convert x[b][c][n] fp32 -> xbt[b][n][c] bf16.
// k_rank's proven LDS-rotation skeleton (conflict-free both phases).
// ---------------------------------------------------------------------------
__global__ __launch_bounds__(256) void k_xpose(
    const float* __restrict__ x, u16* __restrict__ xbt)
{
  __shared__ float tile[32 * 512];        // 64 KiB
  const int n0 = blockIdx.x * 512, c0 = blockIdx.y * 32, b = blockIdx.z;
  const int t = threadIdx.x;
#pragma unroll
  for (int i = 0; i < 16; ++i) {
    int f4 = t + i * 256;                 // 4096 float4 = 32 rows x 128 col4
    int row = f4 >> 7, col4 = f4 & 127;
    float4 v = *(const float4*)(x + ((size_t)(b * CDIM + c0 + row)) * NTOK + n0 + col4 * 4);
    int phys4 = (col4 + row + (row >> 3)) & 127;
    *(float4*)&tile[row * 512 + phys4 * 4] = v;
  }
  __syncthreads();
#pragma unroll
  for (int i = 0; i < 8; ++i) {
    int nr = (t >> 2) + i * 64;
    int cs = (t & 3) * 8;
    float w[8];
#pragma unroll
    for (int j = 0; j < 8; ++j) {
      int row = cs + j;
      int phys4 = ((nr >> 2) + row + (row >> 3)) & 127;
      w[j] = tile[row * 512 + phys4 * 4 + (nr & 3)];
    }
    uint4 o;
    o.x = pack2(w[0], w[1]); o.y = pack2(w[2], w[3]);
    o.z = pack2(w[4], w[5]); o.w = pack2(w[6], w[7]);
    *(uint4*)(xbt + ((size_t)(b * NTOK + n0 + nr)) * CDIM + c0 + cs) = o;
  }
}

// ---------------------------------------------------------------------------
// K1: logits[b][k][n] = sum_c w0[k][c]*x[c][n] + b0[k]  via bf16 MFMA.
// A = w0bf[k][c] (64x512), B = xbt[n][c]; both K-contig (k_conv2 pattern).
// Block: 64k x 128n, 4 waves each 64k x 32n. Bias fused in epilogue.
// ---------------------------------------------------------------------------
__global__ __launch_bounds__(256) void k_logits(
    const u16* __restrict__ w0bf, const u16* __restrict__ xbt,
    const float* __restrict__ b0, float* __restrict__ logits)
{
  __shared__ u16 As[64 * 72];
  __shared__ u16 Bs[128 * 72];
  const int nb = blockIdx.x, b = blockIdx.y;
  const int t = threadIdx.x;
  const int wv = t >> 6, lane = t & 63;
  const int quad = lane >> 4, l15 = lane & 15;
  f32x4 acc[4][2];
#pragma unroll
  for (int mi = 0; mi < 4; ++mi)
#pragma unroll
    for (int ni = 0; ni < 2; ++ni) acc[mi][ni] = (f32x4){0.f, 0.f, 0.f, 0.f};

  for (int kc = 0; kc < 8; ++kc) {
#pragma unroll
    for (int i = 0; i < 2; ++i) {
      int ch = t + i * 256;               // 512 chunks of 8 bf16 (A: 64x64)
      int row = ch >> 3, col = (ch & 7) * 8;
      uint4 a = *(const uint4*)(w0bf + (size_t)row * CDIM + kc * 64 + col);
      *(uint4*)&As[row * 72 + col] = a;
    }
#pragma unroll
    for (int i = 0; i < 4; ++i) {
      int ch = t + i * 256;               // 1024 chunks (B: 128x64)
      int row = ch >> 3, col = (ch & 7) * 8;
      uint4 bb = *(const uint4*)(xbt + ((size_t)(b * NTOK + nb * 128 + row)) * CDIM + kc * 64 + col);
      *(uint4*)&Bs[row * 72 + col] = bb;
    }
    __syncthreads();
#pragma unroll
    for (int kk = 0; kk < 2; ++kk) {
      short8 af[4], bf_[2];
#pragma unroll
      for (int mi = 0; mi < 4; ++mi)
        af[mi] = *(short8*)&As[(mi * 16 + l15) * 72 + kk * 32 + quad * 8];
#pragma unroll
      for (int ni = 0; ni < 2; ++ni)
        bf_[ni] = *(short8*)&Bs[(wv * 32 + ni * 16 + l15) * 72 + kk * 32 + quad * 8];
#pragma unroll
      for (int mi = 0; mi < 4; ++mi)
#pragma unroll
        for (int ni = 0; ni < 2; ++ni)
          acc[mi][ni] = __builtin_amdgcn_mfma_f32_16x16x32_bf16(
              af[mi], bf_[ni], acc[mi][ni], 0, 0, 0);
    }
    __syncthreads();
  }
  // epilogue: + b0[k]   (C/D: col=lane&15, row=quad*4+reg)
#pragma unroll
  for (int mi = 0; mi < 4; ++mi) {
#pragma unroll
    for (int ni = 0; ni < 2; ++ni) {
#pragma unroll
      for (int r = 0; r < 4; ++r) {
        int row = mi * 16 + quad * 4 + r;            // latent k
        int col = nb * 128 + wv * 32 + ni * 16 + l15; // token n
        logits[((size_t)(b * KLAT + row)) * NTOK + col] = acc[mi][ni][r] + b0[row];
      }
    }
  }
}

// ---------------------------------------------------------------------------
// K2: in-place softmax over n (4096) per (b,k) row. 1024 blocks.
// ---------------------------------------------------------------------------
__global__ __launch_bounds__(256) void k_softmax(float* __restrict__ attn)
{
  __shared__ float red[4], red2[4];
  const int t = threadIdx.x;
  float* p = attn + (size_t)blockIdx.x * NTOK;
  float4 v[4];
#pragma unroll
  for (int i = 0; i < 4; ++i) v[i] = ((float4*)p)[t + i * 256];
  float m = v[0].x;
#pragma unroll
  for (int i = 0; i < 4; ++i)
    m = fmaxf(m, fmaxf(fmaxf(v[i].x, v[i].y), fmaxf(v[i].z, v[i].w)));
#pragma unroll
  for (int o = 1; o < 64; o <<= 1) m = fmaxf(m, __shfl_xor(m, o));
  const int wv = t >> 6, lane = t & 63;
  if (lane == 0) red[wv] = m;
  __syncthreads();
  m = fmaxf(fmaxf(red[0], red[1]), fmaxf(red[2], red[3]));
  float s = 0.f;
#pragma unroll
  for (int i = 0; i < 4; ++i) {
    v[i].x = __expf(v[i].x - m); s += v[i].x;
    v[i].y = __expf(v[i].y - m); s += v[i].y;
    v[i].z = __expf(v[i].z - m); s += v[i].z;
    v[i].w = __expf(v[i].w - m); s += v[i].w;
  }
#pragma unroll
  for (int o = 1; o < 64; o <<= 1) s += __shfl_xor(s, o);
  if (lane == 0) red2[wv] = s;
  __syncthreads();
  s = red2[0] + red2[1] + red2[2] + red2[3];
  const float inv = 1.f / s;
#pragma unroll
  for (int i = 0; i < 4; ++i) {
    v[i].x *= inv; v[i].y *= inv; v[i].z *= inv; v[i].w *= inv;
    ((float4*)p)[t + i * 256] = v[i];
  }
}

// ---------------------------------------------------------------------------
// K3: y2[b][c][n] = (sum_k lin1T[k][c]*attn[k][n]) / (1e-9 + sum_k attn[k][n])
// tile: 64k x 256n attn in LDS (64KB); block handles 128 c. y2 := d_out scratch.
// ---------------------------------------------------------------------------
__global__ __launch_bounds__(256) void k_lin1(
    const float* __restrict__ attn, const float* __restrict__ lin1t,
    float* __restrict__ y2)
{
  __shared__ float as_[KLAT][256];
  const int n0 = blockIdx.x * 256, c0 = blockIdx.y * 128, b = blockIdx.z;
  const int t = threadIdx.x;
#pragma unroll
  for (int i = 0; i < 16; ++i) {
    int f4 = t + i * 256;                 // 4096 float4
    int row = f4 >> 6, col = (f4 & 63) * 4;
    float4 v = *(const float4*)(attn + ((size_t)(b * KLAT + row)) * NTOK + n0 + col);
    *(float4*)&as_[row][col] = v;
  }
  __syncthreads();
  {
    float s = 0.f;
#pragma unroll
    for (int k = 0; k < KLAT; ++k) s += as_[k][t];
    float inv = 1.f / (1e-9f + s);
#pragma unroll
    for (int k = 0; k < KLAT; ++k) as_[k][t] *= inv;
  }
  __syncthreads();
  for (int cb = 0; cb < 4; ++cb) {
    const int cbase = c0 + cb * 32;
    float acc[32];
#pragma unroll
    for (int i = 0; i < 32; ++i) acc[i] = 0.f;
    for (int k = 0; k < KLAT; ++k) {
      float av = as_[k][t];
      const float* lp = lin1t + k * CDIM + cbase;  // uniform -> s_load
#pragma unroll
      for (int i = 0; i < 32; ++i) acc[i] = fmaf(lp[i], av, acc[i]);
    }
    float* op = y2 + ((size_t)(b * CDIM + cbase)) * NTOK + n0 + t;
#pragma unroll
    for (int i = 0; i < 32; ++i) op[(size_t)i * NTOK] = acc[i];
  }
}

// ---------------------------------------------------------------------------
// K4: rank + transpose. Each contiguous 512-chunk (fixed b,c; 512 n) gets its
// 256th-largest as threshold; scale 0.75/1.25; write yr^T[b][n][c] bf16.
// Count via __popcll(__ballot(key>=mid)) -- scalar-pipe reduction, no shfl.
// ---------------------------------------------------------------------------
__global__ __launch_bounds__(256) void k_rank(
    const float* __restrict__ y2, u16* __restrict__ yrt)
{
  __shared__ float tile[32 * 512];        // exactly 64 KiB
  const int n0 = blockIdx.x * 512, c0 = blockIdx.y * 32, b = blockIdx.z;
  const int t = threadIdx.x;
  // global -> LDS (rotated layout): phys_col4 = (col4 + row + (row>>3)) & 127
#pragma unroll
  for (int i = 0; i < 16; ++i) {
    int f4 = t + i * 256;                 // 4096 float4 = 32 rows x 128 col4
    int row = f4 >> 7, col4 = f4 & 127;
    float4 v = *(const float4*)(y2 + ((size_t)(b * CDIM + c0 + row)) * NTOK + n0 + col4 * 4);
    int phys4 = (col4 + row + (row >> 3)) & 127;
    *(float4*)&tile[row * 512 + phys4 * 4] = v;
  }
  __syncthreads();
  const int wv = t >> 6, lane = t & 63;
  for (int r = 0; r < 8; ++r) {
    const int row = wv * 8 + r;
    const int rot = row + (row >> 3);
    const int c4a = (lane + rot) & 127;          // logical col4 = lane
    const int c4b = (64 + lane + rot) & 127;     // logical col4 = 64 + lane
    float* pa = &tile[row * 512 + c4a * 4];
    float* pb = &tile[row * 512 + c4b * 4];
    float4 va = *(const float4*)pa;
    float4 vb = *(const float4*)pb;
    float v[8] = {va.x, va.y, va.z, va.w, vb.x, vb.y, vb.z, vb.w};
    u32 key[8];
#pragma unroll
    for (int j = 0; j < 8; ++j) {
      u32 u = __float_as_uint(v[j]);
      key[j] = (u & 0x80000000u) ? ~u : (u | 0x80000000u);
    }
    // binary search for threshold key: invariant cnt(>=lo) >= 256 > cnt(>=hi+1)
    u32 lo = 0u, hi = 0xFFFFFFFFu;
    u32 thr;
    for (;;) {
      u32 d = hi - lo;
      u32 mid = lo + (d >> 1) + (d & 1u);
      int cnt = 0;
#pragma unroll
      for (int j = 0; j < 8; ++j)
        cnt += (int)__popcll(__ballot(key[j] >= mid));
      if (cnt == 256) { thr = mid; break; }   // mid in (v257, v256]: exact classes
      if (cnt > 256) lo = mid; else hi = mid - 1u;
      if (lo >= hi) { thr = lo; break; }      // exact v256 (duplicate-safe)
    }
    float4 oa, ob;
    oa.x = (key[0] < thr) ? 0.75f * v[0] : 1.25f * v[0];
    oa.y = (key[1] < thr) ? 0.75f * v[1] : 1.25f * v[1];
    oa.z = (key[2] < thr) ? 0.75f * v[2] : 1.25f * v[2];
    oa.w = (key[3] < thr) ? 0.75f * v[3] : 1.25f * v[3];
    ob.x = (key[4] < thr) ? 0.75f * v[4] : 1.25f * v[4];
    ob.y = (key[5] < thr) ? 0.75f * v[5] : 1.25f * v[5];
    ob.z = (key[6] < thr) ? 0.75f * v[6] : 1.25f * v[6];
    ob.w = (key[7] < thr) ? 0.75f * v[7] : 1.25f * v[7];
    *(float4*)pa = oa;
    *(float4*)pb = ob;
  }
  __syncthreads();
  // transposed bf16 write: yrt[b][n][c]; read rotated layout
#pragma unroll
  for (int i = 0; i < 8; ++i) {
    int nr = (t >> 2) + i * 64;
    int cs = (t & 3) * 8;
    float w[8];
#pragma unroll
    for (int j = 0; j < 8; ++j) {
      int row = cs + j;
      int phys4 = ((nr >> 2) + row + (row >> 3)) & 127;
      w[j] = tile[row * 512 + phys4 * 4 + (nr & 3)];
    }
    uint4 o;
    o.x = pack2(w[0], w[1]); o.y = pack2(w[2], w[3]);
    o.z = pack2(w[4], w[5]); o.w = pack2(w[6], w[7]);
    *(uint4*)(yrt + ((size_t)(b * NTOK + n0 + nr)) * CDIM + c0 + cs) = o;
  }
}

// ---------------------------------------------------------------------------
// K5: out = relu(relu(conv2_w @ yr) + x).  bf16 MFMA 16x16x32, 128x128 tile,
// BK=64, 4 waves each 64x64. A = cw_bf [o][c], B = yr^T [n][c] (both K-contig).
// ---------------------------------------------------------------------------
__global__ __launch_bounds__(256) void k_conv2(
    const u16* __restrict__ cwbf, const u16* __restrict__ yrt,
    const float* __restrict__ x, float* __restrict__ out)
{
  __shared__ u16 As[128 * 72];            // pitch 72 bf16 (pad 8) -> 144B rows
  __shared__ u16 Bs[128 * 72];
  const int nb = blockIdx.x, mb = blockIdx.y, b = blockIdx.z;
  const int t = threadIdx.x;
  const int wv = t >> 6, lane = t & 63;
  const int wm = wv >> 1, wn = wv & 1;
  const int quad = lane >> 4, l15 = lane & 15;
  f32x4 acc[4][4];
#pragma unroll
  for (int mi = 0; mi < 4; ++mi)
#pragma unroll
    for (int ni = 0; ni < 4; ++ni) acc[mi][ni] = (f32x4){0.f, 0.f, 0.f, 0.f};

  for (int kc = 0; kc < 8; ++kc) {
#pragma unroll
    for (int i = 0; i < 4; ++i) {
      int ch = t + i * 256;               // 1024 chunks of 8 bf16
      int row = ch >> 3, col = (ch & 7) * 8;
      uint4 a = *(const uint4*)(cwbf + ((size_t)(mb * 128 + row)) * CDIM + kc * 64 + col);
      *(uint4*)&As[row * 72 + col] = a;
      uint4 bb = *(const uint4*)(yrt + ((size_t)(b * NTOK + nb * 128 + row)) * CDIM + kc * 64 + col);
      *(uint4*)&Bs[row * 72 + col] = bb;
    }
    __syncthreads();
#pragma unroll
    for (int kk = 0; kk < 2; ++kk) {
      short8 af[4], bf_[4];
#pragma unroll
      for (int mi = 0; mi < 4; ++mi)
        af[mi] = *(short8*)&As[(wm * 64 + mi * 16 + l15) * 72 + kk * 32 + quad * 8];
#pragma unroll
      for (int ni = 0; ni < 4; ++ni)
        bf_[ni] = *(short8*)&Bs[(wn * 64 + ni * 16 + l15) * 72 + kk * 32 + quad * 8];
#pragma unroll
      for (int mi = 0; mi < 4; ++mi)
#pragma unroll
        for (int ni = 0; ni < 4; ++ni)
          acc[mi][ni] = __builtin_amdgcn_mfma_f32_16x16x32_bf16(
              af[mi], bf_[ni], acc[mi][ni], 0, 0, 0);
    }
    __syncthreads();
  }
  // epilogue: relu -> +x -> relu   (C/D layout: col=lane&15, row=quad*4+reg)
#pragma unroll
  for (int mi = 0; mi < 4; ++mi) {
#pragma unroll
    for (int ni = 0; ni < 4; ++ni) {
#pragma unroll
      for (int r = 0; r < 4; ++r) {
        int row = mb * 128 + wm * 64 + mi * 16 + quad * 4 + r;
        int col = nb * 128 + wn * 64 + ni * 16 + l15;
        size_t off = ((size_t)(b * CDIM + row)) * NTOK + col;
        float g = fmaxf(acc[mi][ni][r], 0.f) + x[off];
        out[off] = fmaxf(g, 0.f);
      }
    }
  }
}

// ---------------------------------------------------------------------------
extern "C" void kernel_launch(void* const* d_in, const int* in_sizes, int n_in,
                              void* d_out, int out_size, void* d_ws, size_t ws_size,
                              hipStream_t stream)
{
  const float* x       = (const float*)d_in[0];
  const float* conv1_w = (const float*)d_in[1];
  const float* conv1_b = (const float*)d_in[2];
  const float* lin0_w  = (const float*)d_in[3];
  const float* lin1_w  = (const float*)d_in[4];
  const float* conv2_w = (const float*)d_in[5];
  float* out = (float*)d_out;

  char* ws = (char*)d_ws;
  float* attn  = (float*)ws;                               // 16,777,216 B
  u16*   xbt   = (u16*)(ws + 16777216);                    // 67,108,864 B (dead after k_logits)
  u16*   yrt   = xbt;                                      // reused by k_rank/k_conv2
  char*  wsm   = ws + 16777216 + 67108864;
  u16*   w0bf  = (u16*)wsm;                                // 131072 B  (64x512 bf16... 2B each = 65536 elems)
  float* b0    = (float*)(wsm + 131072);                   // 256 B
  float* lin1t = (float*)(wsm + 131328);                   // 131072 B
  u16*   cwbf  = (u16*)(wsm + 262400);                     // 524288 B
  float* y2    = out;                                      // reuse d_out as scratch

  k_setup  <<<225, 256, 0, stream>>>(conv1_w, conv1_b, lin0_w, lin1_w, conv2_w,
                                     w0bf, b0, lin1t, cwbf);
  k_xpose  <<<dim3(8, 16, 16), 256, 0, stream>>>(x, xbt);
  k_logits <<<dim3(32, 16), 256, 0, stream>>>(w0bf, xbt, b0, attn);
  k_softmax<<<1024, 256, 0, stream>>>(attn);
  k_lin1   <<<dim3(16, 4, 16), 256, 0, stream>>>(attn, lin1t, y2);
  k_rank   <<<dim3(8, 16, 16), 256, 0, stream>>>(y2, yrt);
  k_conv2  <<<dim3(32, 4, 16), 256, 0, stream>>>(cwbf, yrt, x, out);
}